// Round 7
// baseline (190.665 us; speedup 1.0000x reference)
//
#include <hip/hip_runtime.h>
#include <hip/hip_bf16.h>

#define SEQ   2048
#define EMB   1024
#define NHEAD 16
#define DHEAD 64
#define BATCH 2
#define MTOT  (BATCH*SEQ)   // 4096
#define QT    128           // queries per attention block (4 waves x 32 q)
#define KT    64            // keys per tile
#define NTILE (SEQ/KT)      // 32

typedef __attribute__((ext_vector_type(8))) short s8v;   // 8 bf16 (4 VGPRs)
typedef __attribute__((ext_vector_type(4))) short s4v;   // 4 bf16 (8 B)
typedef __attribute__((ext_vector_type(4))) float f4v;   // 16x16 mfma accum
typedef __attribute__((ext_vector_type(16))) float f16v; // 32x32 mfma accum

__device__ __forceinline__ short f2b(float f) {
    union { float fl; unsigned u; } v; v.fl = f;
    unsigned u = v.u;
    u = (u + 0x7fffu + ((u >> 16) & 1u)) >> 16;   // round-to-nearest-even
    return (short)u;
}
// packed fp32x2 -> bf16x2 (v_cvt_pk_bf16_f32); rounded values also feed the
// softmax denominator (consistency => rounding-mode-agnostic).
__device__ __forceinline__ unsigned pk2(float a, float b) {
    union { __hip_bfloat162 h; unsigned u; } c;
    c.h = __float22bfloat162_rn(float2{a, b});
    return c.u;
}

#if __has_builtin(__builtin_amdgcn_exp2f)
__device__ __forceinline__ float exp2_fast(float x) { return __builtin_amdgcn_exp2f(x); }
#else
__device__ __forceinline__ float exp2_fast(float x) { return exp2f(x); }
#endif

// gfx950 cross-lane half-swap: after the op, a = {lanes<32: old a(lo-half),
// lanes>=32: old b(lo-half)}, b = {lanes<32: old a(hi-half), lanes>=32: old
// b(hi-half)} (dst[32:63] <-> src[0:31]; lane&31 preserved).
__device__ __forceinline__ void pl32swap(unsigned &a, unsigned &b) {
    asm("v_permlane32_swap_b32 %0, %1" : "+v"(a), "+v"(b));
}

// Raw workgroup barrier: LDS-visibility only (lgkmcnt drain), does NOT drain
// vmcnt — outstanding global prefetch loads stay in flight across it.
__device__ __forceinline__ void bar_lds() {
    asm volatile("s_waitcnt lgkmcnt(0)\n\ts_barrier" ::: "memory");
}

// async global->LDS DMA, 16 B/lane; LDS dest = wave-uniform base + lane*16.
__device__ __forceinline__ void gl_lds16(const short* g, short* l) {
    __builtin_amdgcn_global_load_lds(
        (const __attribute__((address_space(1))) void*)g,
        (__attribute__((address_space(3))) void*)l, 16, 0, 0);
}

// ---- fp32 -> bf16 convert + chunk swizzle ----
// Output rows are 1024 bf16 = 16 aligned 128B groups of 8 16B-chunks.
// Chunk c of row r is stored at slot (c&~7) | ((c&7) ^ (r&7)) so that
// global_load_lds' contiguous DMA lands a bank-uniform LDS image.
__global__ __launch_bounds__(256)
void cvt_swz(const float* __restrict__ s0, const float* __restrict__ s1,
             const float* __restrict__ s2, const float* __restrict__ s3,
             const float* __restrict__ s4,
             short* __restrict__ d0, short* __restrict__ d1,
             short* __restrict__ d2, short* __restrict__ d3,
             short* __restrict__ d4)
{
    const int seg = blockIdx.y;
    const float* s = seg == 0 ? s0 : seg == 1 ? s1 : seg == 2 ? s2 : seg == 3 ? s3 : s4;
    short*       d = seg == 0 ? d0 : seg == 1 ? d1 : seg == 2 ? d2 : seg == 3 ? d3 : d4;
    const int nchunk = (seg == 0 ? MTOT * EMB : EMB * EMB) / 8;   // 16B chunks
    const int stride = gridDim.x * 256;
    for (int i = blockIdx.x * 256 + threadIdx.x; i < nchunk; i += stride) {
        const int row = i >> 7;         // 128 chunks per 1024-col row
        const int c   = i & 127;
        const float4 v0 = *(const float4*)(s + (size_t)i * 8);
        const float4 v1 = *(const float4*)(s + (size_t)i * 8 + 4);
        s8v o;
        o[0] = f2b(v0.x); o[1] = f2b(v0.y); o[2] = f2b(v0.z); o[3] = f2b(v0.w);
        o[4] = f2b(v1.x); o[5] = f2b(v1.y); o[6] = f2b(v1.z); o[7] = f2b(v1.w);
        const int cp = (c & ~7) | ((c & 7) ^ (row & 7));
        *(s8v*)(d + (size_t)row * EMB + cp * 8) = o;
    }
}

// NT GEMM via global_load_lds (m97 structure): C = A*W^T + bias.
// A, W are bf16 with swizzled 16B chunks (see cvt_swz). LDS rows unpadded
// (128 B); frag reads address slot (kk*4+quad)^(l16&7) -> bank-uniform.
// FUSED3: 3 matrices (QKV); mat 2 writes V transposed per-head [b][h][d][s].
// mat 0 (Q) output is prescaled by 0.125*log2(e) so attention uses exp2.
template<int NT, bool FUSED3>
__global__ __launch_bounds__(256, 3)
void gemm_bb3(const short* __restrict__ A,
              const short* __restrict__ W0, const short* __restrict__ W1, const short* __restrict__ W2,
              const float* __restrict__ B0, const float* __restrict__ B1, const float* __restrict__ B2,
              void* __restrict__ C0, void* __restrict__ C1, void* __restrict__ C2)
{
    constexpr int JN = NT / 32;
    const int K = EMB, N = EMB;
    const int ntiles = EMB / NT;
    const int mat = blockIdx.x / ntiles;
    const int n0  = (blockIdx.x % ntiles) * NT;
    const int m0  = blockIdx.y * 128;
    const short* W  = (mat == 0) ? W0 : (mat == 1 ? W1 : W2);
    const float* Bi = (mat == 0) ? B0 : (mat == 1 ? B1 : B2);
    void*        C  = (mat == 0) ? C0 : (mat == 1 ? C1 : C2);
    const float qscale = (FUSED3 && mat == 0) ? 0.18033688f : 1.0f;  // 1/8*log2e

    __shared__ __align__(16) short As[128 * 64];
    __shared__ __align__(16) short Ws[NT * 64];

    const int tid  = threadIdx.x;
    const int lane = tid & 63;
    const int wave = tid >> 6;
    const int quad = lane >> 4;
    const int l16  = lane & 15;
    const int l8   = l16 & 7;
    const int wm   = wave >> 1;
    const int wn   = wave & 1;

    f4v acc[4][JN] = {};

    const int srow = lane >> 3;    // staging row within 8-row group
    const int scol = (lane & 7) * 8;

    for (int k0 = 0; k0 < K; k0 += 64) {
        // ---- async DMA staging: A rows wave*32.., W rows wave*(NT/4).. ----
        #pragma unroll
        for (int p = 0; p < 4; ++p) {
            const int rbase = wave * 32 + p * 8;
            gl_lds16(A + (size_t)(m0 + rbase + srow) * K + k0 + scol,
                     As + rbase * 64);
        }
        #pragma unroll
        for (int p = 0; p < NT / 32; ++p) {
            const int rbase = wave * (NT / 4) + p * 8;
            gl_lds16(W + (size_t)(n0 + rbase + srow) * K + k0 + scol,
                     Ws + rbase * 64);
        }
        __syncthreads();   // drains the DMA (vmcnt) + barrier

        #pragma unroll
        for (int kk = 0; kk < 2; ++kk) {
            const int slot = ((kk * 4 + quad) ^ l8) * 8;
            s8v af[4], wf[JN];
            #pragma unroll
            for (int i = 0; i < 4; ++i)
                af[i] = *(const s8v*)(As + (wm * 64 + i * 16 + l16) * 64 + slot);
            #pragma unroll
            for (int j = 0; j < JN; ++j)
                wf[j] = *(const s8v*)(Ws + (wn * (NT / 2) + j * 16 + l16) * 64 + slot);
            #pragma unroll
            for (int i = 0; i < 4; ++i)
                #pragma unroll
                for (int j = 0; j < JN; ++j)
                    acc[i][j] = __builtin_amdgcn_mfma_f32_16x16x32_bf16(
                        af[i], wf[j], acc[i][j], 0, 0, 0);
        }
        __syncthreads();   // all waves done reading before next overwrite
    }

    // C/D layout: col = lane&15 (n), row = quad*4+reg (m)   [m89-verified]
    #pragma unroll
    for (int j = 0; j < JN; ++j) {
        const int n = n0 + wn * (NT / 2) + j * 16 + l16;
        const float bv = Bi[n];
        #pragma unroll
        for (int i = 0; i < 4; ++i) {
            const int mb = m0 + wm * 64 + i * 16 + quad * 4;
            if (FUSED3 && mat == 2) {
                const int bb = mb >> 11, s = mb & 2047;
                s4v ov;
                #pragma unroll
                for (int rr = 0; rr < 4; ++rr) ov[rr] = f2b(acc[i][j][rr] + bv);
                *(s4v*)((short*)C + ((size_t)(bb * 1024 + n)) * SEQ + s) = ov;
            } else if (FUSED3) {
                #pragma unroll
                for (int rr = 0; rr < 4; ++rr)
                    ((short*)C)[(size_t)(mb + rr) * N + n] = f2b((acc[i][j][rr] + bv) * qscale);
            } else {
                #pragma unroll
                for (int rr = 0; rr < 4; ++rr)
                    ((float*)C)[(size_t)(mb + rr) * N + n] = acc[i][j][rr] + bv;
            }
        }
    }
}

// MFMA flash attention v10 — 32x32x16 MFMA to halve LDS read traffic.
// R3-R5 invariant ~50 us = LDS-read-BW bound: every wave reads the full
// 16 KB K+V tile from LDS per tile-step; 16 wave-slots/CU x 32 tiles x
// 16 KB = 8 MB/CU ≈ 41 us at 85 B/cyc (m134). With 32x32x16, one wave's
// B-operand covers 32 q-cols (vs 16), so the same 16 KB of A-fragment
// reads serves 2x the q-rows -> 4 MB/CU ≈ 20 us floor.
// Layouts (m74/m101): C/D col=lane&31, row=(reg&3)+8*(reg>>2)+4*(lane>>5);
// A row=lane&31, k=(lane>>5)*8+e; B col=lane&31, k=(lane>>5)*8+e.
// P redistribution (bit-trace verified): key k=k0+2k1+4k2+8k3+16k4+32k5;
// C-side source u_{k5}[k1+2k3+4k4] @ lane-half k2; B-side dest
// pf[k4+2k5].uu[k1+2k2] @ lane-half k3 => dst word j @ half hi takes
// u[(j&1)+2hi+4(ks&1)] from half (j>>1) = ONE permlane32_swap per
// (even, odd+2) pair: swap(u[0],u[2]) swap(u[1],u[3]) swap(u[4],u[6])
// swap(u[5],u[7]) per 32-key block, 8 swaps/tile total.
// Denominator: 4 ones-MFMA per tile into a 32x32 accum (all rows = sum).
// Staging, XCD affinity, exp2-prescale, chunk swizzle: unchanged from v9.
__global__ __launch_bounds__(256, 2)
void attn_mfma10(const short* Q, const short* __restrict__ Kg,
                 const short* __restrict__ Vt, short* O)
{
    // dispatch i -> XCD i&7 (round-robin). Give each XCD 4 (b,h) combos.
    const int i    = blockIdx.x;          // 512 blocks
    const int xcd  = i & 7;
    const int slot = i >> 3;              // 0..63
    const int combo = xcd * 4 + (slot >> 4);   // (b,h) 0..31
    const int qb = slot & 15;                  // 16 q-blocks per (b,h)
    const int h  = combo & 15;
    const int b  = combo >> 4;
    const int q0 = qb * QT;

    const int tid  = threadIdx.x;
    const int lane = tid & 63;
    const int wq   = tid >> 6;            // 0..3, q-cols wq*32..
    const int l32  = lane & 31;
    const int hi   = lane >> 5;
    const int l8   = l32 & 7;

    __shared__ __align__(16) short Ks[2][64 * 64];   // [key][d] swizzled image
    __shared__ __align__(16) short Vs[2][64 * 64];   // [d][key] swizzled image

    // Q B-frags (prescaled by 0.125*log2e): col q = q0+wq*32+l32,
    // k(d) = ds*16 + hi*8 + e
    s8v qf[4];
    #pragma unroll
    for (int ds = 0; ds < 4; ++ds)
        qf[ds] = *(const s8v*)(Q + (size_t)(b * SEQ + q0 + wq * 32 + l32) * EMB
                                 + h * DHEAD + ds * 16 + hi * 8);

    f16v oa0 = {}, oa1 = {};   // O^T[d-block 0/1][q]
    f16v sacc = {};            // ones-MFMA row sums (col=q, all rows equal)
    s8v onef;
    #pragma unroll
    for (int e = 0; e < 8; ++e) onef[e] = (short)0x3F80;   // bf16 1.0

    // ---- DMA staging setup: lane (r,c) covers row r, physical chunk c ----
    const int r = lane >> 3, c = lane & 7;
    const int sc8 = (c ^ (r & 7)) * 8;         // pre-swizzled source chunk
    const bool isK = wq < 2;
    const int wrow = (wq & 1) * 32;            // 32 rows per stager wave
    const size_t kbase = (size_t)(b * SEQ) * EMB + h * DHEAD;
    const size_t vbase = (size_t)((b * NHEAD + h) * DHEAD) * SEQ;
    const short* gsrc = isK ? Kg + kbase + (size_t)(wrow + r) * EMB + sc8
                            : Vt + vbase + (size_t)(wrow + r) * SEQ + sc8;
    const size_t grow8 = isK ? (size_t)8 * EMB : (size_t)8 * SEQ;   // +8 rows
    const size_t tstep = isK ? (size_t)KT * EMB : (size_t)KT;       // +1 tile
    short* const lbase = (isK ? (short*)Ks : (short*)Vs) + wrow * 64;

    // prologue: issue DMA for tile 0 into buf 0 (4 x 1KB per wave)
    #pragma unroll
    for (int p = 0; p < 4; ++p)
        gl_lds16(gsrc + p * grow8, lbase + p * 8 * 64);
    const short* gnext = gsrc + tstep;

    for (int t = 0; t < NTILE; ++t) {
        const int buf = t & 1;
        __syncthreads();   // vmcnt(0)+barrier: tile t landed everywhere;
                           // compute(t-1) done everywhere -> buf^1 is free
        if (t + 1 < NTILE) {
            short* ldst = lbase + (buf ^ 1) * (64 * 64);
            #pragma unroll
            for (int p = 0; p < 4; ++p)
                gl_lds16(gnext + p * grow8, ldst + p * 8 * 64);
            gnext += tstep;
        }
        const short* KsB = Ks[buf];
        const short* VsB = Vs[buf];

        // ---- S^T[key][q] = K · Q^T (log2 domain), 2 key-blocks ----
        f16v sc0 = {}, sc1 = {};
        __builtin_amdgcn_s_setprio(1);
        #pragma unroll
        for (int ds = 0; ds < 4; ++ds) {
            const int ko = ((ds * 2 + hi) ^ l8) * 8;
            const s8v kf0 = *(const s8v*)(KsB + (l32)      * 64 + ko);
            const s8v kf1 = *(const s8v*)(KsB + (32 + l32) * 64 + ko);
            sc0 = __builtin_amdgcn_mfma_f32_32x32x16_bf16(kf0, qf[ds], sc0, 0, 0, 0);
            sc1 = __builtin_amdgcn_mfma_f32_32x32x16_bf16(kf1, qf[ds], sc1, 0, 0, 0);
        }
        __builtin_amdgcn_s_setprio(0);

        // ---- p = 2^s, pack to bf16 pairs (keys consecutive per u32) ----
        unsigned u0[8], u1[8];
        #pragma unroll
        for (int ri = 0; ri < 8; ++ri) {
            u0[ri] = pk2(exp2_fast(sc0[2 * ri]), exp2_fast(sc0[2 * ri + 1]));
            u1[ri] = pk2(exp2_fast(sc1[2 * ri]), exp2_fast(sc1[2 * ri + 1]));
        }

        // ---- key-half exchange: one pl32swap per pair (q stays lane-local)
        pl32swap(u0[0], u0[2]); pl32swap(u0[1], u0[3]);
        pl32swap(u0[4], u0[6]); pl32swap(u0[5], u0[7]);
        pl32swap(u1[0], u1[2]); pl32swap(u1[1], u1[3]);
        pl32swap(u1[4], u1[6]); pl32swap(u1[5], u1[7]);
        union { unsigned uu[4]; s8v s; } pb0, pb1, pb2, pb3;
        pb0.uu[0] = u0[0]; pb0.uu[1] = u0[1]; pb0.uu[2] = u0[2]; pb0.uu[3] = u0[3];
        pb1.uu[0] = u0[4]; pb1.uu[1] = u0[5]; pb1.uu[2] = u0[6]; pb1.uu[3] = u0[7];
        pb2.uu[0] = u1[0]; pb2.uu[1] = u1[1]; pb2.uu[2] = u1[2]; pb2.uu[3] = u1[3];
        pb3.uu[0] = u1[4]; pb3.uu[1] = u1[5]; pb3.uu[2] = u1[6]; pb3.uu[3] = u1[7];

        // ---- O^T[d][q] += V^T[d][key] · P^T ; row sums via ones-MFMA ----
        __builtin_amdgcn_s_setprio(1);
        #pragma unroll
        for (int ks = 0; ks < 4; ++ks) {
            const s8v pf = ks == 0 ? pb0.s : ks == 1 ? pb1.s : ks == 2 ? pb2.s : pb3.s;
            sacc = __builtin_amdgcn_mfma_f32_32x32x16_bf16(onef, pf, sacc, 0, 0, 0);
            const int ko = ((ks * 2 + hi) ^ l8) * 8;
            const s8v vf0 = *(const s8v*)(VsB + (l32)      * 64 + ko);
            const s8v vf1 = *(const s8v*)(VsB + (32 + l32) * 64 + ko);
            oa0 = __builtin_amdgcn_mfma_f32_32x32x16_bf16(vf0, pf, oa0, 0, 0, 0);
            oa1 = __builtin_amdgcn_mfma_f32_32x32x16_bf16(vf1, pf, oa1, 0, 0, 0);
        }
        __builtin_amdgcn_s_setprio(0);
    }

    // ---- denominator: every row of sacc holds the full sum for col q ----
    const float inv = 1.0f / sacc[0];

    __syncthreads();   // everyone done with K/V LDS; reuse Ks region as Os
    short* Os = (short*)Ks;   // 128 rows x 64 shorts = 16 KB
    const int orow = wq * 32 + l32;
    // lane holds q=orow, d = db*32 + (reg&3) + 8*(reg>>2) + 4*hi.
    // s4v pair (reg 4m..4m+3) = d base db*32+8m+4hi, 4 consecutive d.
    #pragma unroll
    for (int db = 0; db < 2; ++db) {
        #pragma unroll
        for (int m = 0; m < 4; ++m) {
            const float a0 = (db ? oa1[4 * m + 0] : oa0[4 * m + 0]) * inv;
            const float a1 = (db ? oa1[4 * m + 1] : oa0[4 * m + 1]) * inv;
            const float a2 = (db ? oa1[4 * m + 2] : oa0[4 * m + 2]) * inv;
            const float a3 = (db ? oa1[4 * m + 3] : oa0[4 * m + 3]) * inv;
            union { unsigned uu[2]; s4v s; } ov;
            ov.uu[0] = pk2(a0, a1);
            ov.uu[1] = pk2(a2, a3);
            // logical chunk db*4+m, in-chunk short 4*hi; phys chunk ^= row&7
            *(s4v*)(Os + orow * 64 + ((db * 4 + m) ^ l8) * 8 + 4 * hi) = ov.s;
        }
    }
    bar_lds();

    // ---- coalesced store: LDS swizzle cancels the output chunk swizzle ----
    const int row = tid >> 1;            // 0..127
    const int cb  = (tid & 1) * 4;       // four physical chunks per thread
    #pragma unroll
    for (int c4 = 0; c4 < 4; ++c4) {
        const int pcc = cb + c4;
        const s8v tt = *(const s8v*)(Os + row * 64 + pcc * 8);
        *(s8v*)(O + (size_t)(b * SEQ + q0 + row) * EMB + h * DHEAD + pcc * 8) = tt;
    }
}

extern "C" void kernel_launch(void* const* d_in, const int* in_sizes, int n_in,
                              void* d_out, int out_size, void* d_ws, size_t ws_size,
                              hipStream_t stream)
{
    const float* x  = (const float*)d_in[0];
    const float* Wq = (const float*)d_in[1];
    const float* bq = (const float*)d_in[2];
    const float* Wk = (const float*)d_in[3];
    const float* bk = (const float*)d_in[4];
    const float* Wv = (const float*)d_in[5];
    const float* bv = (const float*)d_in[6];
    const float* Wo = (const float*)d_in[7];
    const float* bo = (const float*)d_in[8];
    float* out = (float*)d_out;   // fp32 output

    short* xb  = (short*)d_ws;                       // 4096x1024 bf16, swizzled
    short* Wqb = xb  + (size_t)MTOT * EMB;           // swizzled
    short* Wkb = Wqb + (size_t)EMB * EMB;
    short* Wvb = Wkb + (size_t)EMB * EMB;
    short* Wob = Wvb + (size_t)EMB * EMB;
    short* Qw  = Wob + (size_t)EMB * EMB;            // [token][1024] (Q: plain;
                                                     //  then O: swizzled)
    short* Kw  = Qw  + (size_t)MTOT * EMB;           // [token][1024] plain
    short* Vtw = Kw  + (size_t)MTOT * EMB;           // [b][h][d][s] plain

    cvt_swz<<<dim3(512, 5), 256, 0, stream>>>(x, Wq, Wk, Wv, Wo,
                                              xb, Wqb, Wkb, Wvb, Wob);

    gemm_bb3<128, true><<<dim3(24, 32), 256, 0, stream>>>(
        xb, Wqb, Wkb, Wvb, bq, bk, bv, Qw, Kw, Vtw);

    attn_mfma10<<<dim3(BATCH * NHEAD * (SEQ / QT)), 256, 0, stream>>>(Qw, Kw, Vtw, Qw);

    gemm_bb3<64, false><<<dim3(16, 32), 256, 0, stream>>>(
        Qw, Wob, Wob, Wob, bo, bo, bo, out, out, out);
}